// Round 13
// baseline (42.775 us; speedup 1.0000x reference)
//
#include <hip/hip_runtime.h>

// 2-bit child->parent distance per column c (50-bit word): d = (DPACK >> 2c) & 3.
// d==0 -> not a child. Parent of column c is column c-d (d<=3, same row).
#define DPACK 0x00012493939124E4ULL

__global__ __launch_bounds__(256)
void hbfl_kernel(const float* __restrict__ logits,
                 const float* __restrict__ targets,
                 float* __restrict__ partials,
                 unsigned n16, unsigned niter)
{
    __shared__ float wsum[4];

    const unsigned tid = threadIdx.x;
    const unsigned g0 = blockIdx.x * 256u + tid;      // 16-element group index
    const unsigned stride = gridDim.x * 256u;         // 524800; 16*stride % 25 == 0

    // Loop-invariant column phase: rotate the 50-bit DPACK so bit pair j =
    // d(column of this thread's element j). 16 elems -> 32 bits used.
    const unsigned sh = 2u * ((16u * g0) % 25u);
    const unsigned long long rot = (DPACK >> sh) | (DPACK << (50u - sh));
    const unsigned dd = (unsigned)rot;

    const float4* l4p = reinterpret_cast<const float4*>(logits);
    const float4* t4p = reinterpret_cast<const float4*>(targets);

    float acc = 0.0f;

    for (unsigned it = 0u; it < niter; ++it) {
        const unsigned pr = g0 + it * stride;
        const bool valid = (pr < n16);
        const unsigned p  = valid ? pr : (n16 - 1u);  // clamp, mask at accumulate
        const unsigned q  = 4u * p;                   // float4 index

        // One 9-load batch (144 B/lane): all issue before the first waitcnt
        // (within-batch ILP survives compilation; cross-batch never did).
        const float4 xa = l4p[q];
        const float4 xb = l4p[q + 1u];
        const float4 xc = l4p[q + 2u];
        const float4 xd = l4p[q + 3u];
        const float4 ta = t4p[q];
        const float4 tb = t4p[q + 1u];
        const float4 tc = t4p[q + 2u];
        const float4 td = t4p[q + 3u];
        const float4 tp = t4p[q - (unsigned)(q != 0u)];  // prev 16B; clamped @0

        const float xs[16] = {xa.x,xa.y,xa.z,xa.w, xb.x,xb.y,xb.z,xb.w,
                              xc.x,xc.y,xc.z,xc.w, xd.x,xd.y,xd.z,xd.w};
        // Targets window, flat elements 16p-4 .. 16p+15 (w[4+j] = t of elem j).
        const float w20[20] = {tp.x,tp.y,tp.z,tp.w, ta.x,ta.y,ta.z,ta.w,
                               tb.x,tb.y,tb.z,tb.w, tc.x,tc.y,tc.z,tc.w,
                               td.x,td.y,td.z,td.w};

        float a = 0.0f;
        #pragma unroll
        for (int j = 0; j < 16; ++j) {
            const float x = xs[j];
            const float t = w20[4 + j];
            // Binary targets (t in {0,1}): e = exp(-x*(2t-1));
            // bce = ln(1+e); pt = 1/(1+e); 1-pt = e*pt.   (R5-verified math)
            const float sgn = __builtin_fmaf(2.0f, t, -1.0f);
            const float e   = __expf(-x * sgn);
            const float den = 1.0f + e;
            const float pt  = __builtin_amdgcn_rcpf(den);
            const float bce = __logf(den);
            const float omp = e * pt;                     // 1 - pt
            const float fo  = omp * omp * bce;            // focal / ALPHA
            float wgt = __builtin_fmaf(t, 0.375f, 0.1875f); // ALPHA*classw
            const unsigned dj = (dd >> (2 * j)) & 3u;
            // parent target of elem j at window index 4+j-dj (static selects)
            const float tpar = (dj == 1u) ? w20[3 + j]
                             : (dj == 2u) ? w20[2 + j]
                                          : w20[1 + j];
            const bool dbl = (dj != 0u) & (x > 0.5f) & (tpar < 0.5f);
            wgt = dbl ? wgt + wgt : wgt;                  // (1 + penalty)
            a = __builtin_fmaf(fo, wgt, a);
        }
        acc += valid ? a : 0.0f;
    }

    // 64-lane shuffle reduce -> 4-word LDS -> one PLAIN STORE per block
    // (same-address atomics were R1-R11's serial tail).
    #pragma unroll
    for (int off = 32; off > 0; off >>= 1)
        acc += __shfl_down(acc, off);

    const int wid = tid >> 6;
    if ((tid & 63u) == 0u) wsum[wid] = acc;
    __syncthreads();
    if (tid == 0u)
        partials[blockIdx.x] = wsum[0] + wsum[1] + wsum[2] + wsum[3];
}

__global__ __launch_bounds__(256)
void reduce_kernel(const float* __restrict__ partials,
                   float* __restrict__ out,
                   unsigned nparts, float scale)
{
    __shared__ float wsum[4];
    const unsigned tid = threadIdx.x;
    float a = 0.0f;
    for (unsigned i = tid; i < nparts; i += 256u) a += partials[i];
    #pragma unroll
    for (int off = 32; off > 0; off >>= 1)
        a += __shfl_down(a, off);
    const int wid = tid >> 6;
    if ((tid & 63u) == 0u) wsum[wid] = a;
    __syncthreads();
    if (tid == 0u)
        out[0] = (wsum[0] + wsum[1] + wsum[2] + wsum[3]) * scale;
}

extern "C" void kernel_launch(void* const* d_in, const int* in_sizes, int n_in,
                              void* d_out, int out_size, void* d_ws, size_t ws_size,
                              hipStream_t stream)
{
    const float* logits  = (const float*)d_in[0];
    const float* targets = (const float*)d_in[1];
    float* out = (float*)d_out;
    float* ws  = (float*)d_ws;                   // 2050 floats of scratch

    const unsigned n   = (unsigned)in_sizes[0];  // 25,000,000 (divisible by 16? no: /16 = 1,562,500 exactly) 
    const unsigned n16 = n / 16u;                // 1,562,500 groups of 16
    const float scale = 1.0f / (float)n;

    // 2050 = 25*82: element stride (gridDim*256*16) ≡ 0 mod 25 -> per-thread
    // column phase loop-invariant; 3 iterations per thread, tail masked.
    const unsigned nblocks = 2050u;
    const unsigned stride  = nblocks * 256u;
    const unsigned niter   = (n16 + stride - 1u) / stride;   // = 3

    // Stage 1 writes every ws[0..2049] each call; stage 2 reads them and
    // overwrites out[0] (covers the 0xAA poison) -- deterministic.
    hbfl_kernel<<<nblocks, 256, 0, stream>>>(logits, targets, ws, n16, niter);
    reduce_kernel<<<1, 256, 0, stream>>>(ws, out, nblocks, scale);
}